// Round 17
// baseline (218.228 us; speedup 1.0000x reference)
//
#include <hip/hip_runtime.h>
#include <hip/hip_cooperative_groups.h>
namespace cg = cooperative_groups;

#define NB 8
#define NC 19
#define HW (512*512)
#define NPIX (NB*HW)
#define HHW (HW/2)          // 131072
#define RANK 183500u        // max(100000, int(262144*0.7)), < n_pix-1
#define NBIN 4096
#define CAP  4096
#define OFFB 69696          // window-B shift (px): byte delta 0x44100 spreads slice bits

__device__ __forceinline__ unsigned fkey(float f) {
    unsigned b = __float_as_uint(f);
    return (b & 0x80000000u) ? ~b : (b | 0x80000000u);
}
__device__ __forceinline__ float finv(unsigned u) {
    unsigned b = (u & 0x80000000u) ? (u & 0x7fffffffu) : ~u;
    return __uint_as_float(b);
}
__device__ __forceinline__ int bin_of(float l) {
    int b = (int)((l + 1.0f) * 224.0f);
    return b < 0 ? 0 : (b > NBIN - 1 ? NBIN - 1 : b);
}
__device__ __forceinline__ unsigned umn(unsigned a, unsigned b) { return a < b ? a : b; }
__device__ __forceinline__ unsigned umx(unsigned a, unsigned b) { return a > b ? a : b; }

// ---------------- Kernel 1: CE losses (R15 VERBATIM, absmax=0, ~67 us) -------
// Two slice-spread windows per thread, counted-vmcnt pipeline, asm-opaque
// scalar loads, batch from blockIdx only (SGPR bases). Prologue: blocks 0..32
// zero ghist+count+present (consumed only by the tail kernel).
__global__ __launch_bounds__(256) void losses_kernel(
    const float* __restrict__ logits, const int* __restrict__ targets,
    float* __restrict__ losses, unsigned* __restrict__ wszero)
{
    const int blk = blockIdx.x, tid = threadIdx.x;
    if (blk < 33) {   // zero ghist (32768 u32) + count (8) + present (8)
        int j = blk * 1024 + tid * 4;
        if (j < 32784) *reinterpret_cast<uint4*>(wszero + j) = make_uint4(0u,0u,0u,0u);
    }
    const int b  = blk >> 9;                       // batch: blockIdx-only (uniform)
    const int r  = ((blk & 511) << 8) + tid;       // [0, HHW) — lane-varying
    const int rB = (r + OFFB) & (HHW - 1);
    const int pA = (b << 18) + r;
    const int pB = (b << 18) + HHW + rB;
    const float* cb = logits + (size_t)b * NC * HW;   // batch base (SGPR)
    const int*   tb = targets + (size_t)b * HW;
    const unsigned vA = (unsigned)(r * 4);
    const unsigned vB = (unsigned)((HHW + rB) * 4);

    int tA, tB;
    float xA[NC], xB[NC];
    asm volatile("global_load_dword %0, %1, %2" : "=v"(tA) : "v"(vA), "s"(tb));
    asm volatile("global_load_dword %0, %1, %2" : "=v"(tB) : "v"(vB), "s"(tb));
    #pragma unroll
    for (int c = 0; c < NC; ++c)
        asm volatile("global_load_dword %0, %1, %2"
                     : "=v"(xA[c]) : "v"(vA), "s"(cb + (size_t)c * HW));
    #pragma unroll
    for (int c = 0; c < NC; ++c)
        asm volatile("global_load_dword %0, %1, %2"
                     : "=v"(xB[c]) : "v"(vB), "s"(cb + (size_t)c * HW));

    asm volatile("s_waitcnt vmcnt(19)" ::: "memory");
    __builtin_amdgcn_sched_barrier(0);

    {   // ---- window A ----
        float m = xA[0];
        #pragma unroll
        for (int c = 1; c < NC; ++c) m = fmaxf(m, xA[c]);
        float s = 0.f, et = 0.f;
        #pragma unroll
        for (int c = 0; c < NC; ++c) {
            float e = expf(xA[c] - m);
            s += e;
            if (c == tA) et = e;
        }
        losses[pA] = (tA >= 0 && tA < NC) ? -logf(et / s + 1e-7f) : 0.f;
    }

    __builtin_amdgcn_sched_barrier(0);
    asm volatile("s_waitcnt vmcnt(1)" ::: "memory");
    __builtin_amdgcn_sched_barrier(0);

    {   // ---- window B ----
        float m = xB[0];
        #pragma unroll
        for (int c = 1; c < NC; ++c) m = fmaxf(m, xB[c]);
        float s = 0.f, et = 0.f;
        #pragma unroll
        for (int c = 0; c < NC; ++c) {
            float e = expf(xB[c] - m);
            s += e;
            if (c == tB) et = e;
        }
        losses[pB] = (tB >= 0 && tB < NC) ? -logf(et / s + 1e-7f) : 0.f;
    }
}

// ---------------- Kernel 2: fused tail (cooperative, 512 blocks) -------------
// Each thread owns 16 consecutive-chunk losses (float4 x 4, kept in registers
// across grid syncs). Phases: hist+presence -> sync -> pick+compact -> sync ->
// exact select (blocks 0..7) -> sync -> emit. All phase bodies are the passing
// R15 kernels' code operating on registers instead of re-read memory.
// Capacity headroom: LDS 26.7KB -> 5 blocks/CU; VGPR ~50 -> >=1280 blocks max.
__global__ __launch_bounds__(256, 3) void tail_kernel(
    const float* __restrict__ losses, const int* __restrict__ targets,
    float* __restrict__ out,
    unsigned* __restrict__ ghist, unsigned* __restrict__ count,
    unsigned* __restrict__ present, unsigned* __restrict__ info,
    float* __restrict__ thresh, float* __restrict__ cand)
{
    __shared__ unsigned lh[NBIN];      // 16 KB; reused as key array in phase F
    __shared__ unsigned h2[512];
    __shared__ unsigned sub[2048];
    __shared__ unsigned red[8];
    __shared__ unsigned wsum[4], woff[4];
    __shared__ unsigned sh_T, sh_kmin, sh_shift, sh_sb, sh_r2, sh_cnt, pres;

    const int blk = blockIdx.x, tid = threadIdx.x;
    cg::grid_group grid = cg::this_grid();
    const int b    = blk >> 6;          // 64 blocks/batch
    const int cblk = blk & 63;
    const int lane = tid & 63, wid = tid >> 6;

    // ========== H: load 16 losses to registers, LDS hist + presence =========
    for (int j = tid; j < NBIN; j += 256) lh[j] = 0;
    if (tid == 0) pres = 0u;
    __syncthreads();
    const float4* Lp = reinterpret_cast<const float4*>(losses + (size_t)b * HW)
                       + (size_t)cblk * 1024;
    const int4*   Tp = reinterpret_cast<const int4*>(targets + (size_t)b * HW)
                       + (size_t)cblk * 1024;
    float4 L[4];
    unsigned bits = 0u;
    #pragma unroll
    for (int it = 0; it < 4; ++it) {
        L[it] = Lp[it * 256 + tid];
        int4 tv = Tp[it * 256 + tid];
        atomicAdd(&lh[bin_of(L[it].x)], 1u);
        atomicAdd(&lh[bin_of(L[it].y)], 1u);
        atomicAdd(&lh[bin_of(L[it].z)], 1u);
        atomicAdd(&lh[bin_of(L[it].w)], 1u);
        if (tv.x >= 0 && tv.x < NC) bits |= 1u << tv.x;
        if (tv.y >= 0 && tv.y < NC) bits |= 1u << tv.y;
        if (tv.z >= 0 && tv.z < NC) bits |= 1u << tv.z;
        if (tv.w >= 0 && tv.w < NC) bits |= 1u << tv.w;
    }
    #pragma unroll
    for (int o = 1; o < 64; o <<= 1) bits |= __shfl_xor(bits, o);
    if ((tid & 63) == 0 && bits) atomicOr(&pres, bits);
    __syncthreads();
    {
        unsigned* gh = ghist + b * NBIN;
        for (int j = tid; j < NBIN; j += 256) {
            unsigned v = lh[j];
            if (v) atomicAdd(&gh[j], v);
        }
        if (tid == 0 && pres) atomicOr(&present[b], pres);
    }
    grid.sync();

    // ========== PC: parallel pick + register compact ========================
    {
        const unsigned* gh = ghist + b * NBIN;
        unsigned s = 0;
        #pragma unroll
        for (int j = 0; j < 16; ++j) s += gh[tid * 16 + j];
        unsigned incl = s;
        #pragma unroll
        for (int o = 1; o < 64; o <<= 1) {
            unsigned v = (unsigned)__shfl_up((int)incl, o);
            if (lane >= o) incl += v;
        }
        if (lane == 63) wsum[wid] = incl;
        __syncthreads();
        if (tid == 0) { unsigned c = 0; for (int w = 0; w < 4; ++w) { woff[w] = c; c += wsum[w]; } }
        __syncthreads();
        unsigned excl = woff[wid] + incl - s;
        if (RANK >= excl && RANK < excl + s) {   // exactly one thread per block
            unsigned rr = RANK - excl, cum = 0;
            for (int j = 0; j < 16; ++j) {
                unsigned c = gh[tid * 16 + j];
                if (cum + c > rr) {
                    sh_T = (unsigned)(tid * 16 + j);
                    if (cblk == 0) { info[b * 2] = sh_T; info[b * 2 + 1] = rr - cum; }
                    break;
                }
                cum += c;
            }
        }
        __syncthreads();
        const int T = (int)sh_T;
        #pragma unroll
        for (int it = 0; it < 4; ++it) {
            float vals[4] = {L[it].x, L[it].y, L[it].z, L[it].w};
            #pragma unroll
            for (int q = 0; q < 4; ++q) {
                float val = vals[q];
                bool sel = (bin_of(val) == T);
                unsigned long long msk = __ballot(sel);
                if (msk) {
                    int leader = __ffsll(msk) - 1;
                    int pre = __popcll(msk & ((1ull << lane) - 1ull));
                    unsigned base = 0;
                    if (lane == leader) base = atomicAdd(&count[b], (unsigned)__popcll(msk));
                    base = (unsigned)__shfl((int)base, leader);
                    if (sel) {
                        unsigned idx = base + (unsigned)pre;
                        if (idx < CAP) cand[b * CAP + idx] = val;
                    }
                }
            }
        }
    }
    grid.sync();

    // ========== F: exact tie-aware rank select (blocks 0..7) ================
    if (blk < 8) {
        const int fb = blk;
        unsigned k = count[fb]; if (k > CAP) k = CAP;
        const unsigned r = info[fb * 2 + 1];
        for (unsigned j = tid; j < k; j += 256) lh[j] = fkey(cand[fb * CAP + j]);
        for (int j = tid; j < 512; j += 256) h2[j] = 0;
        __syncthreads();
        unsigned lmin = 0xFFFFFFFFu, lmax = 0u;
        for (unsigned j = tid; j < k; j += 256) { unsigned v = lh[j]; lmin = umn(lmin, v); lmax = umx(lmax, v); }
        #pragma unroll
        for (int o = 1; o < 64; o <<= 1) {
            lmin = umn(lmin, (unsigned)__shfl_xor((int)lmin, o));
            lmax = umx(lmax, (unsigned)__shfl_xor((int)lmax, o));
        }
        if ((tid & 63) == 0) { red[tid >> 6] = lmin; red[4 + (tid >> 6)] = lmax; }
        __syncthreads();
        if (tid == 0) {
            unsigned mn = red[0], mx = red[4];
            for (int w = 1; w < 4; ++w) { mn = umn(mn, red[w]); mx = umx(mx, red[4 + w]); }
            unsigned spread = mx - mn;
            int bits2 = 32 - __clz((int)(spread | 1u));
            sh_shift = (unsigned)(bits2 > 9 ? bits2 - 9 : 0);   // (spread>>shift) < 512
            sh_kmin = mn;
            sh_cnt = 0;
        }
        __syncthreads();
        const unsigned kmin = sh_kmin, shift = sh_shift;
        for (unsigned j = tid; j < k; j += 256) atomicAdd(&h2[(lh[j] - kmin) >> shift], 1u);
        __syncthreads();
        if (tid == 0) {
            unsigned cum = 0; int sb = 0;
            while (sb < 511 && cum + h2[sb] <= r) { cum += h2[sb]; ++sb; }
            sh_sb = (unsigned)sb; sh_r2 = r - cum;
        }
        __syncthreads();
        const unsigned sb = sh_sb;
        for (unsigned j = tid; j < k; j += 256) {
            if (((lh[j] - kmin) >> shift) == sb) {
                unsigned idx = atomicAdd(&sh_cnt, 1u);
                if (idx < 2048) sub[idx] = lh[j];
            }
        }
        __syncthreads();
        const unsigned k2 = umn(sh_cnt, 2048u), r2 = sh_r2;
        for (unsigned e = tid; e < k2; e += 256) {
            unsigned v = sub[e], less = 0, eq = 0;
            for (unsigned j = 0; j < k2; ++j) { unsigned u = sub[j]; less += (u < v); eq += (u == v); }
            if (less <= r2 && r2 < less + eq) thresh[fb] = finv(v);
        }
    }
    grid.sync();

    // ========== E: emit flags from registers ================================
    {
        const float th = thresh[b];
        const unsigned pm = present[b];
        float4* Op = reinterpret_cast<float4*>(out + (size_t)b * HW)
                     + (size_t)cblk * 1024;
        #pragma unroll
        for (int it = 0; it < 4; ++it) {
            const int p0 = (cblk * 1024 + it * 256 + tid) * 4;
            float4 o;
            o.x = ((L[it].x > th) || ((p0 + 0) < NC && ((pm >> (p0 + 0)) & 1u))) ? 1.f : 0.f;
            o.y = ((L[it].y > th) || ((p0 + 1) < NC && ((pm >> (p0 + 1)) & 1u))) ? 1.f : 0.f;
            o.z = ((L[it].z > th) || ((p0 + 2) < NC && ((pm >> (p0 + 2)) & 1u))) ? 1.f : 0.f;
            o.w = ((L[it].w > th) || ((p0 + 3) < NC && ((pm >> (p0 + 3)) & 1u))) ? 1.f : 0.f;
            Op[it * 256 + tid] = o;
        }
    }
}

extern "C" void kernel_launch(void* const* d_in, const int* in_sizes, int n_in,
                              void* d_out, int out_size, void* d_ws, size_t ws_size,
                              hipStream_t stream)
{
    const float* logits  = (const float*)d_in[0];
    const int*   targets = (const int*)d_in[1];
    float* out = (float*)d_out;   // doubles as the losses buffer (NPIX floats)

    // ws layout: [ghist 32768 u32][count 8][present 8][info 16][thresh 8][cand 8*4096 f32]
    char* ws = (char*)d_ws;
    unsigned* ghist   = (unsigned*)(ws);                 // 131072 B
    unsigned* count   = (unsigned*)(ws + 131072);
    unsigned* present = (unsigned*)(ws + 131104);
    unsigned* info    = (unsigned*)(ws + 131136);
    float*    thresh  = (float*)   (ws + 131200);
    float*    cand    = (float*)   (ws + 131232);

    // no memset: losses_kernel blocks 0..32 zero ghist+count+present

    losses_kernel<<<NPIX / 512, 256, 0, stream>>>(logits, targets, out, ghist);

    const float* lin = out;
    void* args[] = { (void*)&lin, (void*)&targets, (void*)&out,
                     (void*)&ghist, (void*)&count, (void*)&present,
                     (void*)&info, (void*)&thresh, (void*)&cand };
    hipLaunchCooperativeKernel((void*)tail_kernel, dim3(512), dim3(256),
                               args, 0, stream);
}